// Round 1
// baseline (7248.344 us; speedup 1.0000x reference)
//
#include <hip/hip_runtime.h>
#include <hip/hip_bf16.h>
#include <math.h>

#define NN 50000
#define NE 1600000
#define HIDC 128
#define NG 512

__device__ __forceinline__ float sigmoidf_(float x){ return 1.0f/(1.0f+__expf(-x)); }
__device__ __forceinline__ float softplusf_(float x){ return fmaxf(x,0.0f) + log1pf(__expf(-fabsf(x))); }

// ---------------- init: h1 = x, zero pool sums/counts ----------------
__global__ __launch_bounds__(256) void init_k(const float* __restrict__ x, float* __restrict__ h1,
                                              float* __restrict__ sums, float* __restrict__ counts){
  int i = blockIdx.x*256 + threadIdx.x;
  if (i < NN*3) h1[i] = x[i];
  if (i < NG*HIDC) sums[i] = 0.0f;
  if (i < NG) counts[i] = 0.0f;
}

// ---------------- conv1: channels=3, one thread per edge ----------------
__global__ __launch_bounds__(256) void conv1_k(const int* __restrict__ srcp, const int* __restrict__ dstp,
    const float* __restrict__ x, const float* __restrict__ ea,
    const float* __restrict__ W1f, const float* __restrict__ b1f,
    const float* __restrict__ W1s, const float* __restrict__ b1s,
    float* __restrict__ out, int E)
{
  __shared__ float wf[114], wsm[114], bfs[6];
  int tid = threadIdx.x;
  if (tid < 114){ wf[tid]=W1f[tid]; wsm[tid]=W1s[tid]; }
  if (tid < 3){ bfs[tid]=b1f[tid]; bfs[3+tid]=b1s[tid]; }
  __syncthreads();
  int ei = blockIdx.x*256+tid;
  if (ei >= E) return;
  int s = srcp[ei], d = dstp[ei];
  float F[3], S[3];
  #pragma unroll
  for (int c=0;c<3;++c){ F[c]=bfs[c]; S[c]=bfs[3+c]; }
  #pragma unroll
  for (int j=0;j<3;++j){
    float xd = x[d*3+j], xs = x[s*3+j];
    #pragma unroll
    for (int c=0;c<3;++c){
      F[c] = fmaf(xd, wf[j*3+c], F[c]);
      F[c] = fmaf(xs, wf[(3+j)*3+c], F[c]);
      S[c] = fmaf(xd, wsm[j*3+c], S[c]);
      S[c] = fmaf(xs, wsm[(3+j)*3+c], S[c]);
    }
  }
  const float4* ep = reinterpret_cast<const float4*>(ea + (size_t)ei*32);
  #pragma unroll
  for (int q=0;q<8;++q){
    float4 v = ep[q];
    float evs[4] = {v.x,v.y,v.z,v.w};
    #pragma unroll
    for (int t=0;t<4;++t){
      int k = q*4+t;
      #pragma unroll
      for (int c=0;c<3;++c){
        F[c] = fmaf(evs[t], wf[(6+k)*3+c], F[c]);
        S[c] = fmaf(evs[t], wsm[(6+k)*3+c], S[c]);
      }
    }
  }
  #pragma unroll
  for (int c=0;c<3;++c){
    float m = sigmoidf_(F[c])*softplusf_(S[c]);
    unsafeAtomicAdd(&out[d*3+c], m);
  }
}

// ---------------- proj: h = relu(h1 @ Wp + bp), K=3 ----------------
__global__ __launch_bounds__(256) void proj_k(const float* __restrict__ h1, const float* __restrict__ Wp,
                                              const float* __restrict__ bp, float* __restrict__ h)
{
  int gid = blockIdx.x*256+threadIdx.x;
  int n = gid >> 7, c = gid & 127;
  float v = bp[c];
  v = fmaf(h1[n*3+0], Wp[c],       v);
  v = fmaf(h1[n*3+1], Wp[128+c],   v);
  v = fmaf(h1[n*3+2], Wp[256+c],   v);
  h[gid] = fmaxf(v, 0.0f);
}

// ---------------- gemm_ab: Af=X@Wf[0:128]+bf, Bf=X@Wf[128:256], As=X@Ws[0:128]+bs, Bs=X@Ws[128:256]
// X:[N,128]. Block: 32 rows x 128 cols, 256 threads, thread = 4 rows x 4 cols.
__global__ __launch_bounds__(256) void gemm_ab_k(const float* __restrict__ X,
    const float* __restrict__ Wf, const float* __restrict__ bf,
    const float* __restrict__ Ws, const float* __restrict__ bs,
    float* __restrict__ Af, float* __restrict__ Bf, float* __restrict__ As, float* __restrict__ Bs, int N)
{
  __shared__ float hs[32*128];
  __shared__ float wt[32*128];
  int tid = threadIdx.x;
  int base = blockIdx.x * 32;
  // stage X tile (32x128), clamp rows
  #pragma unroll
  for (int q = 0; q < 4; ++q) {
    int j = tid + q*256;            // float4 index, 0..1023
    int row = base + (j>>5);
    int r = row < N ? row : N-1;
    reinterpret_cast<float4*>(hs)[j] = reinterpret_cast<const float4*>(X + (size_t)r*128)[j & 31];
  }
  int c4 = (tid & 31) * 4;
  int rg4 = (tid >> 5) * 4;         // row group base (0,4,...,28)
  const float* Wsrc[4] = {Wf, Wf + 128*128, Ws, Ws + 128*128};
  float* Out[4]        = {Af, Bf, As, Bs};
  for (int w = 0; w < 4; ++w) {
    float4 bias = make_float4(0,0,0,0);
    if (w == 0) bias = *reinterpret_cast<const float4*>(bf + c4);
    if (w == 2) bias = *reinterpret_cast<const float4*>(bs + c4);
    float4 acc[4];
    #pragma unroll
    for (int i=0;i<4;++i) acc[i] = bias;
    const float* W = Wsrc[w];
    for (int k0 = 0; k0 < 128; k0 += 32) {
      __syncthreads();
      #pragma unroll
      for (int q = 0; q < 4; ++q) {
        int j = tid + q*256;
        reinterpret_cast<float4*>(wt)[j] = reinterpret_cast<const float4*>(W + (size_t)k0*128)[j];
      }
      __syncthreads();
      #pragma unroll
      for (int k = 0; k < 32; ++k) {
        float4 wv = *reinterpret_cast<const float4*>(&wt[k*128 + c4]);
        #pragma unroll
        for (int i=0;i<4;++i){
          float a = hs[(rg4+i)*128 + k0 + k];
          acc[i].x = fmaf(a, wv.x, acc[i].x);
          acc[i].y = fmaf(a, wv.y, acc[i].y);
          acc[i].z = fmaf(a, wv.z, acc[i].z);
          acc[i].w = fmaf(a, wv.w, acc[i].w);
        }
      }
    }
    float* O = Out[w];
    #pragma unroll
    for (int i=0;i<4;++i) {
      int row = base + rg4 + i;
      if (row < N) *reinterpret_cast<float4*>(&O[(size_t)row*128 + c4]) = acc[i];
    }
  }
}

// ---------------- edge conv (HID channels): gate = sigmoid(F)*softplus(S), atomic scatter to dst
// F = Af[dst]+Bf[src]+e@Wf_e (+bias folded in Af). Block: 256 thr, 32 edges/pass, 8 passes.
#define EPB 256
#define PASS 32
__global__ __launch_bounds__(256) void edge_conv_k(const int* __restrict__ srcp, const int* __restrict__ dstp,
   const float* __restrict__ ea, const float* __restrict__ Wf, const float* __restrict__ Ws,
   const float* __restrict__ Af, const float* __restrict__ Bf, const float* __restrict__ As, const float* __restrict__ Bs,
   float* __restrict__ out, int E)
{
  __shared__ float wfe[32*128];
  __shared__ float wse[32*128];
  __shared__ float el[PASS*32];
  __shared__ int ss[PASS], dd[PASS];
  int tid = threadIdx.x;
  // stage edge-part weights: rows 256..287 of the 288x128 matrices
  #pragma unroll
  for (int q=0;q<4;++q){
    reinterpret_cast<float4*>(wfe)[tid + q*256] = reinterpret_cast<const float4*>(Wf + 256*128)[tid + q*256];
    reinterpret_cast<float4*>(wse)[tid + q*256] = reinterpret_cast<const float4*>(Ws + 256*128)[tid + q*256];
  }
  int c4  = (tid & 31) * 4;
  int rep = tid >> 5;               // 0..7, each handles 4 edges of the pass
  long e0 = (long)blockIdx.x * EPB;
  for (int p = 0; p < EPB; p += PASS) {
    long pb = e0 + p;
    __syncthreads();
    { // stage edge attrs: PASS*32 floats = 256 float4
      long eidx = pb + (tid >> 3);
      if (eidx < E)
        reinterpret_cast<float4*>(el)[tid] = reinterpret_cast<const float4*>(ea)[eidx*8 + (tid&7)];
    }
    if (tid < PASS){
      long eidx = pb + tid;
      ss[tid] = eidx < E ? srcp[eidx] : 0;
      dd[tid] = eidx < E ? dstp[eidx] : 0;
    }
    __syncthreads();
    float4 F[4], S[4];
    int dl[4];
    #pragma unroll
    for (int e=0;e<4;++e){
      int eloc = rep*4 + e;
      int s = ss[eloc], d = dd[eloc];
      dl[e] = d;
      float4 af  = *reinterpret_cast<const float4*>(&Af[(size_t)d*128 + c4]);
      float4 bf4 = *reinterpret_cast<const float4*>(&Bf[(size_t)s*128 + c4]);
      float4 as  = *reinterpret_cast<const float4*>(&As[(size_t)d*128 + c4]);
      float4 bs4 = *reinterpret_cast<const float4*>(&Bs[(size_t)s*128 + c4]);
      F[e] = make_float4(af.x+bf4.x, af.y+bf4.y, af.z+bf4.z, af.w+bf4.w);
      S[e] = make_float4(as.x+bs4.x, as.y+bs4.y, as.z+bs4.z, as.w+bs4.w);
    }
    #pragma unroll
    for (int k=0;k<32;++k){
      float4 wf4 = *reinterpret_cast<const float4*>(&wfe[k*128 + c4]);
      float4 ws4 = *reinterpret_cast<const float4*>(&wse[k*128 + c4]);
      #pragma unroll
      for (int e=0;e<4;++e){
        float ev = el[(rep*4+e)*32 + k];
        F[e].x = fmaf(ev, wf4.x, F[e].x);
        F[e].y = fmaf(ev, wf4.y, F[e].y);
        F[e].z = fmaf(ev, wf4.z, F[e].z);
        F[e].w = fmaf(ev, wf4.w, F[e].w);
        S[e].x = fmaf(ev, ws4.x, S[e].x);
        S[e].y = fmaf(ev, ws4.y, S[e].y);
        S[e].z = fmaf(ev, ws4.z, S[e].z);
        S[e].w = fmaf(ev, ws4.w, S[e].w);
      }
    }
    #pragma unroll
    for (int e=0;e<4;++e){
      long eidx = pb + rep*4 + e;
      if (eidx < E){
        int d = dl[e];
        float m0 = sigmoidf_(F[e].x)*softplusf_(S[e].x);
        float m1 = sigmoidf_(F[e].y)*softplusf_(S[e].y);
        float m2 = sigmoidf_(F[e].z)*softplusf_(S[e].z);
        float m3 = sigmoidf_(F[e].w)*softplusf_(S[e].w);
        unsafeAtomicAdd(&out[(size_t)d*128 + c4 + 0], m0);
        unsafeAtomicAdd(&out[(size_t)d*128 + c4 + 1], m1);
        unsafeAtomicAdd(&out[(size_t)d*128 + c4 + 2], m2);
        unsafeAtomicAdd(&out[(size_t)d*128 + c4 + 3], m3);
      }
    }
  }
}

// ---------------- relu inplace ----------------
__global__ __launch_bounds__(256) void relu_k(float* __restrict__ p, int n){
  int i = blockIdx.x*256+threadIdx.x;
  if (i<n) p[i] = fmaxf(p[i],0.0f);
}

// ---------------- pool: relu(h3) -> atomic mean prep ----------------
__global__ __launch_bounds__(256) void pool_k(const float* __restrict__ h3, const int* __restrict__ batch,
                                              float* __restrict__ sums, float* __restrict__ counts)
{
  int gid = blockIdx.x*256+threadIdx.x;
  int n = gid>>7, c = gid&127;
  int b = batch[n];
  float v = fmaxf(h3[gid], 0.0f);
  unsafeAtomicAdd(&sums[(size_t)b*128+c], v);
  if (c==0) unsafeAtomicAdd(&counts[b], 1.0f);
}

// ---------------- final: mean -> fc1(relu) -> 5 heads ----------------
__global__ __launch_bounds__(128) void final_k(const float* __restrict__ sums, const float* __restrict__ counts,
    const float* __restrict__ Wfc, const float* __restrict__ bfc,
    const float* __restrict__ Wh, const float* __restrict__ bh, float* __restrict__ outp)
{
  __shared__ float mean[128];
  __shared__ float gv[128];
  int g = blockIdx.x, t = threadIdx.x;
  float cnt = fmaxf(counts[g], 1.0f);
  mean[t] = sums[(size_t)g*128+t] / cnt;
  __syncthreads();
  float acc = bfc[t];
  #pragma unroll 8
  for (int k=0;k<128;++k) acc = fmaf(mean[k], Wfc[k*128+t], acc);
  gv[t] = fmaxf(acc, 0.0f);
  __syncthreads();
  if (t < 5){
    float o = bh[t];
    for (int k=0;k<128;++k) o = fmaf(gv[k], Wh[k*5+t], o);
    outp[g*5+t] = o;
  }
}

extern "C" void kernel_launch(void* const* d_in, const int* in_sizes, int n_in,
                              void* d_out, int out_size, void* d_ws, size_t ws_size,
                              hipStream_t stream) {
  const float* x    = (const float*)d_in[0];
  const float* ea   = (const float*)d_in[1];
  const int*   eidx = (const int*)  d_in[2];
  const int*   batch= (const int*)  d_in[3];
  const float* W1f  = (const float*)d_in[4];
  const float* b1f  = (const float*)d_in[5];
  const float* W1s  = (const float*)d_in[6];
  const float* b1s  = (const float*)d_in[7];
  const float* Wp   = (const float*)d_in[8];
  const float* bp   = (const float*)d_in[9];
  const float* W2f  = (const float*)d_in[10];
  const float* b2f  = (const float*)d_in[11];
  const float* W2s  = (const float*)d_in[12];
  const float* b2s  = (const float*)d_in[13];
  const float* W3f  = (const float*)d_in[14];
  const float* b3f  = (const float*)d_in[15];
  const float* W3s  = (const float*)d_in[16];
  const float* b3s  = (const float*)d_in[17];
  const float* Wfc  = (const float*)d_in[18];
  const float* bfc  = (const float*)d_in[19];
  const float* Wh   = (const float*)d_in[20];
  const float* bh   = (const float*)d_in[21];

  int E = in_sizes[2]/2;
  const int* srcp = eidx;
  const int* dstp = eidx + E;

  float* ws = (float*)d_ws;
  size_t o = 0;
  float* h1   = ws + o; o += 150016;
  float* h    = ws + o; o += (size_t)NN*128;
  float* h2   = ws + o; o += (size_t)NN*128;
  float* Af   = ws + o; o += (size_t)NN*128;
  float* Bf   = ws + o; o += (size_t)NN*128;
  float* As   = ws + o; o += (size_t)NN*128;
  float* Bs   = ws + o; o += (size_t)NN*128;
  float* sums = ws + o; o += (size_t)NG*128;
  float* cnts = ws + o; o += 512;

  int ngAB   = (NN + 31)/32;
  int ngNode = (NN*128)/256;           // 25000
  int ngE1   = (E + 255)/256;          // 6250
  int ngEc   = (E + EPB - 1)/EPB;      // 6250

  // 0) init
  init_k<<<(NN*3 + 255)/256, 256, 0, stream>>>(x, h1, sums, cnts);
  // 1) conv1
  conv1_k<<<ngE1, 256, 0, stream>>>(srcp, dstp, x, ea, W1f, b1f, W1s, b1s, h1, E);
  // 2) proj
  proj_k<<<ngNode, 256, 0, stream>>>(h1, Wp, bp, h);
  // 3) conv2 node terms
  gemm_ab_k<<<ngAB, 256, 0, stream>>>(h, W2f, b2f, W2s, b2s, Af, Bf, As, Bs, NN);
  // 4) h2 = h (scatter init)
  hipMemcpyAsync(h2, h, (size_t)NN*128*sizeof(float), hipMemcpyDeviceToDevice, stream);
  // 5) conv2 edges
  edge_conv_k<<<ngEc, 256, 0, stream>>>(srcp, dstp, ea, W2f, W2s, Af, Bf, As, Bs, h2, E);
  // 6) relu
  relu_k<<<ngNode, 256, 0, stream>>>(h2, NN*128);
  // 7) conv3 node terms
  gemm_ab_k<<<ngAB, 256, 0, stream>>>(h2, W3f, b3f, W3s, b3s, Af, Bf, As, Bs, NN);
  // 8) h3(reuse h) = h2
  hipMemcpyAsync(h, h2, (size_t)NN*128*sizeof(float), hipMemcpyDeviceToDevice, stream);
  // 9) conv3 edges
  edge_conv_k<<<ngEc, 256, 0, stream>>>(srcp, dstp, ea, W3f, W3s, Af, Bf, As, Bs, h, E);
  // 10) pool (relu fused)
  pool_k<<<ngNode, 256, 0, stream>>>(h, batch, sums, cnts);
  // 11) final
  final_k<<<NG, 128, 0, stream>>>(sums, cnts, Wfc, bfc, Wh, bh, (float*)d_out);
}

// Round 4
// 3690.622 us; speedup vs baseline: 1.9640x; 1.9640x over previous
//
#include <hip/hip_runtime.h>
#include <hip/hip_bf16.h>
#include <math.h>

#define NN 50000
#define NE 1600000
#define HIDC 128
#define NG 512

__device__ __forceinline__ float sigmoidf_(float x){ return 1.0f/(1.0f+__expf(-x)); }
__device__ __forceinline__ float softplusf_(float x){ return fmaxf(x,0.0f) + log1pf(__expf(-fabsf(x))); }

// ---------------- init: h1 = x, zero pool sums/counts, zero deg ----------------
__global__ __launch_bounds__(256) void init_k(const float* __restrict__ x, float* __restrict__ h1,
                                              float* __restrict__ sums, float* __restrict__ counts,
                                              int* __restrict__ deg){
  int i = blockIdx.x*256 + threadIdx.x;
  if (i < NN*3) h1[i] = x[i];
  if (i < NG*HIDC) sums[i] = 0.0f;
  if (i < NG) counts[i] = 0.0f;
  if (i < NN) deg[i] = 0;
}

// ---------------- CSR build ----------------
__global__ __launch_bounds__(256) void hist_k(const int* __restrict__ dstp, int* __restrict__ deg, int E){
  int i = blockIdx.x*256 + threadIdx.x;
  if (i < E) atomicAdd(&deg[dstp[i]], 1);
}

// single block, 1024 threads: exclusive scan of deg -> rowptr, cursor
__global__ __launch_bounds__(1024) void scan_k(const int* __restrict__ deg, int* __restrict__ rowptr,
                                               int* __restrict__ cursor){
  __shared__ int wsum[16];
  __shared__ int carry_s;
  int tid = threadIdx.x, lane = tid & 63, w = tid >> 6;
  if (tid == 0) carry_s = 0;
  __syncthreads();
  for (int c0 = 0; c0 < NN; c0 += 1024){
    int i = c0 + tid;
    int v = (i < NN) ? deg[i] : 0;
    int x = v;
    #pragma unroll
    for (int off = 1; off < 64; off <<= 1){ int t = __shfl_up(x, off); if (lane >= off) x += t; }
    if (lane == 63) wsum[w] = x;
    __syncthreads();
    if (w == 0){
      int y = (lane < 16) ? wsum[lane] : 0;
      #pragma unroll
      for (int off = 1; off < 16; off <<= 1){ int t = __shfl_up(y, off); if (lane >= off) y += t; }
      if (lane < 16) wsum[lane] = y;
    }
    __syncthreads();
    int waveoff = (w > 0) ? wsum[w-1] : 0;
    int excl = carry_s + waveoff + x - v;
    if (i < NN){ rowptr[i] = excl; cursor[i] = excl; }
    __syncthreads();
    if (tid == 0) carry_s += wsum[15];
    __syncthreads();
  }
  if (threadIdx.x == 0) rowptr[NN] = carry_s;
}

__global__ __launch_bounds__(256) void perm_k(const int* __restrict__ srcp, const int* __restrict__ dstp,
                                              int* __restrict__ cursor, int* __restrict__ srcs,
                                              int* __restrict__ eids, int E){
  int i = blockIdx.x*256 + threadIdx.x;
  if (i < E){
    int d = dstp[i];
    int pos = atomicAdd(&cursor[d], 1);
    srcs[pos] = srcp[i];
    eids[pos] = i;
  }
}

// ---------------- conv1: channels=3, one thread per edge (atomic; cheap at 3ch) ----------------
__global__ __launch_bounds__(256) void conv1_k(const int* __restrict__ srcp, const int* __restrict__ dstp,
    const float* __restrict__ x, const float* __restrict__ ea,
    const float* __restrict__ W1f, const float* __restrict__ b1f,
    const float* __restrict__ W1s, const float* __restrict__ b1s,
    float* __restrict__ out, int E)
{
  __shared__ float wf[114], wsm[114], bfs[6];
  int tid = threadIdx.x;
  if (tid < 114){ wf[tid]=W1f[tid]; wsm[tid]=W1s[tid]; }
  if (tid < 3){ bfs[tid]=b1f[tid]; bfs[3+tid]=b1s[tid]; }
  __syncthreads();
  int ei = blockIdx.x*256+tid;
  if (ei >= E) return;
  int s = srcp[ei], d = dstp[ei];
  float F[3], S[3];
  #pragma unroll
  for (int c=0;c<3;++c){ F[c]=bfs[c]; S[c]=bfs[3+c]; }
  #pragma unroll
  for (int j=0;j<3;++j){
    float xd = x[d*3+j], xs = x[s*3+j];
    #pragma unroll
    for (int c=0;c<3;++c){
      F[c] = fmaf(xd, wf[j*3+c], F[c]);
      F[c] = fmaf(xs, wf[(3+j)*3+c], F[c]);
      S[c] = fmaf(xd, wsm[j*3+c], S[c]);
      S[c] = fmaf(xs, wsm[(3+j)*3+c], S[c]);
    }
  }
  const float4* ep = reinterpret_cast<const float4*>(ea + (size_t)ei*32);
  #pragma unroll
  for (int q=0;q<8;++q){
    float4 v = ep[q];
    float evs[4] = {v.x,v.y,v.z,v.w};
    #pragma unroll
    for (int t=0;t<4;++t){
      int k = q*4+t;
      #pragma unroll
      for (int c=0;c<3;++c){
        F[c] = fmaf(evs[t], wf[(6+k)*3+c], F[c]);
        S[c] = fmaf(evs[t], wsm[(6+k)*3+c], S[c]);
      }
    }
  }
  #pragma unroll
  for (int c=0;c<3;++c){
    float m = sigmoidf_(F[c])*softplusf_(S[c]);
    unsafeAtomicAdd(&out[d*3+c], m);
  }
}

// ---------------- proj: h = relu(h1 @ Wp + bp), K=3 ----------------
__global__ __launch_bounds__(256) void proj_k(const float* __restrict__ h1, const float* __restrict__ Wp,
                                              const float* __restrict__ bp, float* __restrict__ h)
{
  int gid = blockIdx.x*256+threadIdx.x;
  int n = gid >> 7, c = gid & 127;
  float v = bp[c];
  v = fmaf(h1[n*3+0], Wp[c],       v);
  v = fmaf(h1[n*3+1], Wp[128+c],   v);
  v = fmaf(h1[n*3+2], Wp[256+c],   v);
  h[gid] = fmaxf(v, 0.0f);
}

// ---------------- gemm_ab: Af=X@Wf[0:128]+bf, Bf=X@Wf[128:256], As=X@Ws[0:128]+bs, Bs=X@Ws[128:256]
__global__ __launch_bounds__(256) void gemm_ab_k(const float* __restrict__ X,
    const float* __restrict__ Wf, const float* __restrict__ bf,
    const float* __restrict__ Ws, const float* __restrict__ bs,
    float* __restrict__ Af, float* __restrict__ Bf, float* __restrict__ As, float* __restrict__ Bs, int N)
{
  __shared__ float hs[32*128];
  __shared__ float wt[32*128];
  int tid = threadIdx.x;
  int base = blockIdx.x * 32;
  #pragma unroll
  for (int q = 0; q < 4; ++q) {
    int j = tid + q*256;
    int row = base + (j>>5);
    int r = row < N ? row : N-1;
    reinterpret_cast<float4*>(hs)[j] = reinterpret_cast<const float4*>(X + (size_t)r*128)[j & 31];
  }
  int c4 = (tid & 31) * 4;
  int rg4 = (tid >> 5) * 4;
  const float* Wsrc[4] = {Wf, Wf + 128*128, Ws, Ws + 128*128};
  float* Out[4]        = {Af, Bf, As, Bs};
  for (int w = 0; w < 4; ++w) {
    float4 bias = make_float4(0,0,0,0);
    if (w == 0) bias = *reinterpret_cast<const float4*>(bf + c4);
    if (w == 2) bias = *reinterpret_cast<const float4*>(bs + c4);
    float4 acc[4];
    #pragma unroll
    for (int i=0;i<4;++i) acc[i] = bias;
    const float* W = Wsrc[w];
    for (int k0 = 0; k0 < 128; k0 += 32) {
      __syncthreads();
      #pragma unroll
      for (int q = 0; q < 4; ++q) {
        int j = tid + q*256;
        reinterpret_cast<float4*>(wt)[j] = reinterpret_cast<const float4*>(W + (size_t)k0*128)[j];
      }
      __syncthreads();
      #pragma unroll
      for (int k = 0; k < 32; ++k) {
        float4 wv = *reinterpret_cast<const float4*>(&wt[k*128 + c4]);
        #pragma unroll
        for (int i=0;i<4;++i){
          float a = hs[(rg4+i)*128 + k0 + k];
          acc[i].x = fmaf(a, wv.x, acc[i].x);
          acc[i].y = fmaf(a, wv.y, acc[i].y);
          acc[i].z = fmaf(a, wv.z, acc[i].z);
          acc[i].w = fmaf(a, wv.w, acc[i].w);
        }
      }
    }
    float* O = Out[w];
    #pragma unroll
    for (int i=0;i<4;++i) {
      int row = base + rg4 + i;
      if (row < N) *reinterpret_cast<float4*>(&O[(size_t)row*128 + c4]) = acc[i];
    }
  }
}

// ---------------- CSR edge conv: one wave per dst node, 2 ch/lane, 4 edges/iter ----------------
// F = Af[dst] + Bf[src] + e@Wfe ; m = sigmoid(F)*softplus(S) ; out[dst] = relu(hprev[dst] + sum m)
__global__ __launch_bounds__(256) void conv_csr_k(
    const int* __restrict__ rowptr, const int* __restrict__ srcs, const int* __restrict__ eids,
    const float* __restrict__ ea, const float* __restrict__ Wf, const float* __restrict__ Ws,
    const float* __restrict__ Af, const float* __restrict__ Bf,
    const float* __restrict__ As, const float* __restrict__ Bs,
    const float* __restrict__ hprev, float* __restrict__ out,
    const int* __restrict__ batch, float* __restrict__ sums, float* __restrict__ cnts, int do_pool)
{
  __shared__ float wfe[32*128];
  __shared__ float wse[32*128];
  int tid = threadIdx.x;
  #pragma unroll
  for (int q=0;q<4;++q){
    reinterpret_cast<float4*>(wfe)[tid + q*256] = reinterpret_cast<const float4*>(Wf + 256*128)[tid + q*256];
    reinterpret_cast<float4*>(wse)[tid + q*256] = reinterpret_cast<const float4*>(Ws + 256*128)[tid + q*256];
  }
  __syncthreads();
  int d = blockIdx.x*4 + (tid>>6);       // grid = NN/4 exactly
  int lane = tid & 63;
  int c2 = lane*2;
  int beg = rowptr[d], end = rowptr[d+1];
  float2 afv = *reinterpret_cast<const float2*>(&Af[(size_t)d*128 + c2]);
  float2 asv = *reinterpret_cast<const float2*>(&As[(size_t)d*128 + c2]);
  float2 acc = make_float2(0.f, 0.f);
  int j16 = lane >> 4;                   // which edge this 16-lane cluster stages
  int p   = lane & 15;
  for (int e0 = beg; e0 < end; e0 += 4){
    int nb = end - e0; nb = nb < 4 ? nb : 4;
    int em = 0, sm = 0;
    if (lane < nb){ em = eids[e0+lane]; sm = srcs[e0+lane]; }
    // stage edge attrs: cluster j loads 32 floats of edge j (float2/lane over 16 lanes)
    int erow = __shfl(em, j16);
    float2 ev = make_float2(0.f, 0.f);
    if (j16 < nb) ev = *reinterpret_cast<const float2*>(&ea[(size_t)erow*32 + p*2]);
    float2 Fj[4], Sj[4];
    #pragma unroll
    for (int jj=0;jj<4;++jj){
      int sj = __shfl(sm, jj);
      float2 bfv = make_float2(0.f,0.f), bsv = make_float2(0.f,0.f);
      if (jj < nb){
        bfv = *reinterpret_cast<const float2*>(&Bf[(size_t)sj*128 + c2]);
        bsv = *reinterpret_cast<const float2*>(&Bs[(size_t)sj*128 + c2]);
      }
      Fj[jj] = make_float2(afv.x+bfv.x, afv.y+bfv.y);
      Sj[jj] = make_float2(asv.x+bsv.x, asv.y+bsv.y);
    }
    #pragma unroll
    for (int k=0;k<32;++k){
      float2 wf2 = *reinterpret_cast<const float2*>(&wfe[k*128 + c2]);
      float2 ws2 = *reinterpret_cast<const float2*>(&wse[k*128 + c2]);
      #pragma unroll
      for (int jj=0;jj<4;++jj){
        // e value of edge jj, element k: lives in lane jj*16 + (k>>1), component k&1 (compile-time)
        int evi = __builtin_amdgcn_readlane(__float_as_int((k & 1) ? ev.y : ev.x), jj*16 + (k>>1));
        float evk = __int_as_float(evi);
        Fj[jj].x = fmaf(evk, wf2.x, Fj[jj].x);
        Fj[jj].y = fmaf(evk, wf2.y, Fj[jj].y);
        Sj[jj].x = fmaf(evk, ws2.x, Sj[jj].x);
        Sj[jj].y = fmaf(evk, ws2.y, Sj[jj].y);
      }
    }
    #pragma unroll
    for (int jj=0;jj<4;++jj){
      if (jj < nb){
        acc.x += sigmoidf_(Fj[jj].x)*softplusf_(Sj[jj].x);
        acc.y += sigmoidf_(Fj[jj].y)*softplusf_(Sj[jj].y);
      }
    }
  }
  float2 hv = *reinterpret_cast<const float2*>(&hprev[(size_t)d*128 + c2]);
  float ox = fmaxf(hv.x + acc.x, 0.f);
  float oy = fmaxf(hv.y + acc.y, 0.f);
  if (!do_pool){
    float2 o = make_float2(ox, oy);
    *reinterpret_cast<float2*>(&out[(size_t)d*128 + c2]) = o;
  } else {
    int b = batch[d];
    unsafeAtomicAdd(&sums[(size_t)b*128 + c2 + 0], ox);
    unsafeAtomicAdd(&sums[(size_t)b*128 + c2 + 1], oy);
    if (lane == 0) unsafeAtomicAdd(&cnts[b], 1.0f);
  }
}

// ---------------- final: mean -> fc1(relu) -> 5 heads ----------------
__global__ __launch_bounds__(128) void final_k(const float* __restrict__ sums, const float* __restrict__ counts,
    const float* __restrict__ Wfc, const float* __restrict__ bfc,
    const float* __restrict__ Wh, const float* __restrict__ bh, float* __restrict__ outp)
{
  __shared__ float mean[128];
  __shared__ float gv[128];
  int g = blockIdx.x, t = threadIdx.x;
  float cnt = fmaxf(counts[g], 1.0f);
  mean[t] = sums[(size_t)g*128+t] / cnt;
  __syncthreads();
  float acc = bfc[t];
  #pragma unroll 8
  for (int k=0;k<128;++k) acc = fmaf(mean[k], Wfc[k*128+t], acc);
  gv[t] = fmaxf(acc, 0.0f);
  __syncthreads();
  if (t < 5){
    float o = bh[t];
    for (int k=0;k<128;++k) o = fmaf(gv[k], Wh[k*5+t], o);
    outp[g*5+t] = o;
  }
}

extern "C" void kernel_launch(void* const* d_in, const int* in_sizes, int n_in,
                              void* d_out, int out_size, void* d_ws, size_t ws_size,
                              hipStream_t stream) {
  const float* x    = (const float*)d_in[0];
  const float* ea   = (const float*)d_in[1];
  const int*   eidx = (const int*)  d_in[2];
  const int*   batch= (const int*)  d_in[3];
  const float* W1f  = (const float*)d_in[4];
  const float* b1f  = (const float*)d_in[5];
  const float* W1s  = (const float*)d_in[6];
  const float* b1s  = (const float*)d_in[7];
  const float* Wp   = (const float*)d_in[8];
  const float* bp   = (const float*)d_in[9];
  const float* W2f  = (const float*)d_in[10];
  const float* b2f  = (const float*)d_in[11];
  const float* W2s  = (const float*)d_in[12];
  const float* b2s  = (const float*)d_in[13];
  const float* W3f  = (const float*)d_in[14];
  const float* b3f  = (const float*)d_in[15];
  const float* W3s  = (const float*)d_in[16];
  const float* b3s  = (const float*)d_in[17];
  const float* Wfc  = (const float*)d_in[18];
  const float* bfc  = (const float*)d_in[19];
  const float* Wh   = (const float*)d_in[20];
  const float* bh   = (const float*)d_in[21];

  int E = in_sizes[2]/2;
  const int* srcp = eidx;
  const int* dstp = eidx + E;

  float* ws = (float*)d_ws;
  size_t o = 0;
  float* h1   = ws + o; o += 150016;
  float* h    = ws + o; o += (size_t)NN*128;
  float* h2   = ws + o; o += (size_t)NN*128;
  float* Af   = ws + o; o += (size_t)NN*128;
  float* Bf   = ws + o; o += (size_t)NN*128;
  float* As   = ws + o; o += (size_t)NN*128;
  float* Bs   = ws + o; o += (size_t)NN*128;
  float* sums = ws + o; o += (size_t)NG*128;
  float* cnts = ws + o; o += 512;
  int* iws    = (int*)(ws + o);
  size_t io = 0;
  int* deg    = iws + io; io += NN;
  int* rowptr = iws + io; io += NN + 64;
  int* cursor = iws + io; io += NN;
  int* srcs   = iws + io; io += (size_t)NE;
  int* eids   = iws + io; io += (size_t)NE;

  int ngAB   = (NN + 31)/32;
  int ngNode = (NN*128)/256;
  int ngE    = (E + 255)/256;
  int ngCsr  = NN/4;                    // 12500, exact

  // 0) init (h1=x, zero sums/cnts/deg)
  init_k<<<(NN*3 + 255)/256, 256, 0, stream>>>(x, h1, sums, cnts, deg);
  // 1) CSR build
  hist_k<<<ngE, 256, 0, stream>>>(dstp, deg, E);
  scan_k<<<1, 1024, 0, stream>>>(deg, rowptr, cursor);
  perm_k<<<ngE, 256, 0, stream>>>(srcp, dstp, cursor, srcs, eids, E);
  // 2) conv1 (atomic, 3 ch)
  conv1_k<<<ngE, 256, 0, stream>>>(srcp, dstp, x, ea, W1f, b1f, W1s, b1s, h1, E);
  // 3) proj
  proj_k<<<ngNode, 256, 0, stream>>>(h1, Wp, bp, h);
  // 4) conv2 node terms
  gemm_ab_k<<<ngAB, 256, 0, stream>>>(h, W2f, b2f, W2s, b2s, Af, Bf, As, Bs, NN);
  // 5) conv2 edges (CSR, writes h2 = relu(h + scatter))
  conv_csr_k<<<ngCsr, 256, 0, stream>>>(rowptr, srcs, eids, ea, W2f, W2s, Af, Bf, As, Bs,
                                        h, h2, batch, sums, cnts, 0);
  // 6) conv3 node terms
  gemm_ab_k<<<ngAB, 256, 0, stream>>>(h2, W3f, b3f, W3s, b3s, Af, Bf, As, Bs, NN);
  // 7) conv3 edges + fused relu + pool
  conv_csr_k<<<ngCsr, 256, 0, stream>>>(rowptr, srcs, eids, ea, W3f, W3s, Af, Bf, As, Bs,
                                        h2, h, batch, sums, cnts, 1);
  // 8) final
  final_k<<<NG, 128, 0, stream>>>(sums, cnts, Wfc, bfc, Wh, bh, (float*)d_out);
}

// Round 6
// 2925.922 us; speedup vs baseline: 2.4773x; 1.2614x over previous
//
#include <hip/hip_runtime.h>
#include <hip/hip_bf16.h>
#include <math.h>

#define NN 50000
#define NE 1600000
#define HIDC 128
#define NG 512

typedef __bf16 bf16x8 __attribute__((ext_vector_type(8)));
typedef float f32x4 __attribute__((ext_vector_type(4)));

__device__ __forceinline__ float sigmoidf_(float x){ return 1.0f/(1.0f+__expf(-x)); }
__device__ __forceinline__ float softplusf_(float x){
  return fmaxf(x,0.0f) + __logf(1.0f + __expf(-fabsf(x)));
}
__device__ __forceinline__ unsigned short f2bf_(float f){
  unsigned u = __float_as_uint(f);
  return (unsigned short)((u + 0x7FFFu + ((u>>16)&1u)) >> 16);
}

// ---------------- init: h1 = x, zero pool sums/counts, zero deg ----------------
__global__ __launch_bounds__(256) void init_k(const float* __restrict__ x, float* __restrict__ h1,
                                              float* __restrict__ sums, float* __restrict__ counts,
                                              int* __restrict__ deg){
  int i = blockIdx.x*256 + threadIdx.x;
  if (i < NN*3) h1[i] = x[i];
  if (i < NG*HIDC) sums[i] = 0.0f;
  if (i < NG) counts[i] = 0.0f;
  if (i < NN) deg[i] = 0;
}

// ---------------- CSR build ----------------
__global__ __launch_bounds__(256) void hist_k(const int* __restrict__ dstp, int* __restrict__ deg, int E){
  int i = blockIdx.x*256 + threadIdx.x;
  if (i < E) atomicAdd(&deg[dstp[i]], 1);
}

__global__ __launch_bounds__(1024) void scan_k(const int* __restrict__ deg, int* __restrict__ rowptr,
                                               int* __restrict__ cursor){
  __shared__ int wsum[16];
  __shared__ int carry_s;
  int tid = threadIdx.x, lane = tid & 63, w = tid >> 6;
  if (tid == 0) carry_s = 0;
  __syncthreads();
  for (int c0 = 0; c0 < NN; c0 += 1024){
    int i = c0 + tid;
    int v = (i < NN) ? deg[i] : 0;
    int x = v;
    #pragma unroll
    for (int off = 1; off < 64; off <<= 1){ int t = __shfl_up(x, off); if (lane >= off) x += t; }
    if (lane == 63) wsum[w] = x;
    __syncthreads();
    if (w == 0){
      int y = (lane < 16) ? wsum[lane] : 0;
      #pragma unroll
      for (int off = 1; off < 16; off <<= 1){ int t = __shfl_up(y, off); if (lane >= off) y += t; }
      if (lane < 16) wsum[lane] = y;
    }
    __syncthreads();
    int waveoff = (w > 0) ? wsum[w-1] : 0;
    int excl = carry_s + waveoff + x - v;
    if (i < NN){ rowptr[i] = excl; cursor[i] = excl; }
    __syncthreads();
    if (tid == 0) carry_s += wsum[15];
    __syncthreads();
  }
  if (threadIdx.x == 0) rowptr[NN] = carry_s;
}

__global__ __launch_bounds__(256) void perm_k(const int* __restrict__ srcp, const int* __restrict__ dstp,
                                              int* __restrict__ cursor, int* __restrict__ srcs,
                                              int* __restrict__ eids, int E){
  int i = blockIdx.x*256 + threadIdx.x;
  if (i < E){
    int d = dstp[i];
    int pos = atomicAdd(&cursor[d], 1);
    srcs[pos] = srcp[i];
    eids[pos] = i;
  }
}

// ---------------- conv1: channels=3, one thread per edge ----------------
__global__ __launch_bounds__(256) void conv1_k(const int* __restrict__ srcp, const int* __restrict__ dstp,
    const float* __restrict__ x, const float* __restrict__ ea,
    const float* __restrict__ W1f, const float* __restrict__ b1f,
    const float* __restrict__ W1s, const float* __restrict__ b1s,
    float* __restrict__ out, int E)
{
  __shared__ float wf[114], wsm[114], bfs[6];
  int tid = threadIdx.x;
  if (tid < 114){ wf[tid]=W1f[tid]; wsm[tid]=W1s[tid]; }
  if (tid < 3){ bfs[tid]=b1f[tid]; bfs[3+tid]=b1s[tid]; }
  __syncthreads();
  int ei = blockIdx.x*256+tid;
  if (ei >= E) return;
  int s = srcp[ei], d = dstp[ei];
  float F[3], S[3];
  #pragma unroll
  for (int c=0;c<3;++c){ F[c]=bfs[c]; S[c]=bfs[3+c]; }
  #pragma unroll
  for (int j=0;j<3;++j){
    float xd = x[d*3+j], xs = x[s*3+j];
    #pragma unroll
    for (int c=0;c<3;++c){
      F[c] = fmaf(xd, wf[j*3+c], F[c]);
      F[c] = fmaf(xs, wf[(3+j)*3+c], F[c]);
      S[c] = fmaf(xd, wsm[j*3+c], S[c]);
      S[c] = fmaf(xs, wsm[(3+j)*3+c], S[c]);
    }
  }
  const float4* ep = reinterpret_cast<const float4*>(ea + (size_t)ei*32);
  #pragma unroll
  for (int q=0;q<8;++q){
    float4 v = ep[q];
    float evs[4] = {v.x,v.y,v.z,v.w};
    #pragma unroll
    for (int t=0;t<4;++t){
      int k = q*4+t;
      #pragma unroll
      for (int c=0;c<3;++c){
        F[c] = fmaf(evs[t], wf[(6+k)*3+c], F[c]);
        S[c] = fmaf(evs[t], wsm[(6+k)*3+c], S[c]);
      }
    }
  }
  #pragma unroll
  for (int c=0;c<3;++c){
    float m = sigmoidf_(F[c])*softplusf_(S[c]);
    unsafeAtomicAdd(&out[d*3+c], m);
  }
}

// ---------------- proj: h = relu(h1 @ Wp + bp), K=3 ----------------
__global__ __launch_bounds__(256) void proj_k(const float* __restrict__ h1, const float* __restrict__ Wp,
                                              const float* __restrict__ bp, float* __restrict__ h)
{
  int gid = blockIdx.x*256+threadIdx.x;
  int n = gid >> 7, c = gid & 127;
  float v = bp[c];
  v = fmaf(h1[n*3+0], Wp[c],       v);
  v = fmaf(h1[n*3+1], Wp[128+c],   v);
  v = fmaf(h1[n*3+2], Wp[256+c],   v);
  h[gid] = fmaxf(v, 0.0f);
}

// ---------------- gemm_ab: node-term GEMMs ----------------
__global__ __launch_bounds__(256) void gemm_ab_k(const float* __restrict__ X,
    const float* __restrict__ Wf, const float* __restrict__ bf,
    const float* __restrict__ Ws, const float* __restrict__ bs,
    float* __restrict__ Af, float* __restrict__ Bf, float* __restrict__ As, float* __restrict__ Bs, int N)
{
  __shared__ float hs[32*128];
  __shared__ float wt[32*128];
  int tid = threadIdx.x;
  int base = blockIdx.x * 32;
  #pragma unroll
  for (int q = 0; q < 4; ++q) {
    int j = tid + q*256;
    int row = base + (j>>5);
    int r = row < N ? row : N-1;
    reinterpret_cast<float4*>(hs)[j] = reinterpret_cast<const float4*>(X + (size_t)r*128)[j & 31];
  }
  int c4 = (tid & 31) * 4;
  int rg4 = (tid >> 5) * 4;
  const float* Wsrc[4] = {Wf, Wf + 128*128, Ws, Ws + 128*128};
  float* Out[4]        = {Af, Bf, As, Bs};
  for (int w = 0; w < 4; ++w) {
    float4 bias = make_float4(0,0,0,0);
    if (w == 0) bias = *reinterpret_cast<const float4*>(bf + c4);
    if (w == 2) bias = *reinterpret_cast<const float4*>(bs + c4);
    float4 acc[4];
    #pragma unroll
    for (int i=0;i<4;++i) acc[i] = bias;
    const float* W = Wsrc[w];
    for (int k0 = 0; k0 < 128; k0 += 32) {
      __syncthreads();
      #pragma unroll
      for (int q = 0; q < 4; ++q) {
        int j = tid + q*256;
        reinterpret_cast<float4*>(wt)[j] = reinterpret_cast<const float4*>(W + (size_t)k0*128)[j];
      }
      __syncthreads();
      #pragma unroll
      for (int k = 0; k < 32; ++k) {
        float4 wv = *reinterpret_cast<const float4*>(&wt[k*128 + c4]);
        #pragma unroll
        for (int i=0;i<4;++i){
          float a = hs[(rg4+i)*128 + k0 + k];
          acc[i].x = fmaf(a, wv.x, acc[i].x);
          acc[i].y = fmaf(a, wv.y, acc[i].y);
          acc[i].z = fmaf(a, wv.z, acc[i].z);
          acc[i].w = fmaf(a, wv.w, acc[i].w);
        }
      }
    }
    float* O = Out[w];
    #pragma unroll
    for (int i=0;i<4;++i) {
      int row = base + rg4 + i;
      if (row < N) *reinterpret_cast<float4*>(&O[(size_t)row*128 + c4]) = acc[i];
    }
  }
}

// ---------------- tgemm: T[p][0:128]=ea[eids[p]]@Wf_e, T[p][128:256]=...@Ws_e (bf16 out) ----
// MFMA 16x16x32 bf16. A: 16 edges x 32k; B tile t: 32k x 16 cols. T in CSR position order.
__global__ __launch_bounds__(256) void tgemm_k(const int* __restrict__ eids, const float* __restrict__ ea,
    const float* __restrict__ Wf, const float* __restrict__ Ws,
    unsigned short* __restrict__ Tb, int E)
{
  int lane = threadIdx.x & 63;
  int r = lane & 15, g = lane >> 4;
  int wid  = (blockIdx.x*256 + threadIdx.x) >> 6;
  int nwav = (gridDim.x*256) >> 6;
  int ntiles = (E + 15) >> 4;

  // B fragments: 16 tiles (8 for Wf cols, 8 for Ws cols); lane holds col=lane&15, k=g*8+j
  bf16x8 Bt[16];
  #pragma unroll
  for (int t=0;t<16;++t){
    const float* Wsrc = (t<8) ? Wf : Ws;
    int cb = (t&7)*16 + r;
    #pragma unroll
    for (int j=0;j<8;++j){
      int k = g*8 + j;
      Bt[t][j] = (__bf16)Wsrc[(256+k)*128 + cb];
    }
  }

  for (int tile = wid; tile < ntiles; tile += nwav){
    int p = tile*16 + r;
    int pc = p < E ? p : E-1;
    int eid = eids[pc];
    const float* arow = ea + (size_t)eid*32 + g*8;
    float4 a0 = *reinterpret_cast<const float4*>(arow);
    float4 a1 = *reinterpret_cast<const float4*>(arow + 4);
    bf16x8 A;
    A[0]=(__bf16)a0.x; A[1]=(__bf16)a0.y; A[2]=(__bf16)a0.z; A[3]=(__bf16)a0.w;
    A[4]=(__bf16)a1.x; A[5]=(__bf16)a1.y; A[6]=(__bf16)a1.z; A[7]=(__bf16)a1.w;
    #pragma unroll
    for (int t=0;t<16;++t){
      f32x4 z = {0.f,0.f,0.f,0.f};
      f32x4 d = __builtin_amdgcn_mfma_f32_16x16x32_bf16(A, Bt[t], z, 0, 0, 0);
      #pragma unroll
      for (int q=0;q<4;++q){
        int erow = tile*16 + g*4 + q;       // D row = edge-in-tile, D col = lane&15
        if (erow < E) Tb[(size_t)erow*256 + t*16 + r] = f2bf_(d[q]);
      }
    }
  }
}

// ---------------- conv (T-path): wave per node, lane owns 2 channels ----------------
__global__ __launch_bounds__(256) void conv_t_k(
    const int* __restrict__ rowptr, const int* __restrict__ srcs,
    const unsigned short* __restrict__ Tb,
    const float* __restrict__ Af, const float* __restrict__ Bf,
    const float* __restrict__ As, const float* __restrict__ Bs,
    const float* __restrict__ hprev, float* __restrict__ out,
    const int* __restrict__ batch, float* __restrict__ sums, float* __restrict__ cnts, int do_pool)
{
  int tid = threadIdx.x;
  int d = blockIdx.x*4 + (tid>>6);
  int lane = tid & 63;
  int c2 = lane*2;
  int beg = rowptr[d], end = rowptr[d+1];
  float2 afv = *reinterpret_cast<const float2*>(&Af[(size_t)d*128 + c2]);
  float2 asv = *reinterpret_cast<const float2*>(&As[(size_t)d*128 + c2]);
  float2 acc = make_float2(0.f, 0.f);
  for (int e0 = beg; e0 < end; e0 += 4){
    int nb = end - e0; nb = nb < 4 ? nb : 4;
    int sm = (lane < nb) ? srcs[e0+lane] : 0;
    float2 bfv[4], bsv[4];
    unsigned tf[4], ts[4];
    #pragma unroll
    for (int jj=0;jj<4;++jj){
      int sj = __shfl(sm, jj);
      if (jj < nb){
        bfv[jj] = *reinterpret_cast<const float2*>(&Bf[(size_t)sj*128 + c2]);
        bsv[jj] = *reinterpret_cast<const float2*>(&Bs[(size_t)sj*128 + c2]);
        size_t tb = (size_t)(e0+jj)*256 + c2;
        tf[jj] = *reinterpret_cast<const unsigned*>(Tb + tb);
        ts[jj] = *reinterpret_cast<const unsigned*>(Tb + tb + 128);
      } else {
        bfv[jj] = make_float2(0.f,0.f); bsv[jj] = make_float2(0.f,0.f);
        tf[jj] = 0; ts[jj] = 0;
      }
    }
    #pragma unroll
    for (int jj=0;jj<4;++jj){
      if (jj < nb){
        float tfx = __uint_as_float(tf[jj] << 16);
        float tfy = __uint_as_float(tf[jj] & 0xFFFF0000u);
        float tsx = __uint_as_float(ts[jj] << 16);
        float tsy = __uint_as_float(ts[jj] & 0xFFFF0000u);
        float Fx = afv.x + bfv[jj].x + tfx;
        float Fy = afv.y + bfv[jj].y + tfy;
        float Sx = asv.x + bsv[jj].x + tsx;
        float Sy = asv.y + bsv[jj].y + tsy;
        acc.x += sigmoidf_(Fx)*softplusf_(Sx);
        acc.y += sigmoidf_(Fy)*softplusf_(Sy);
      }
    }
  }
  float2 hv = *reinterpret_cast<const float2*>(&hprev[(size_t)d*128 + c2]);
  float ox = fmaxf(hv.x + acc.x, 0.f);
  float oy = fmaxf(hv.y + acc.y, 0.f);
  if (!do_pool){
    *reinterpret_cast<float2*>(&out[(size_t)d*128 + c2]) = make_float2(ox, oy);
  } else {
    int b = batch[d];
    unsafeAtomicAdd(&sums[(size_t)b*128 + c2 + 0], ox);
    unsafeAtomicAdd(&sums[(size_t)b*128 + c2 + 1], oy);
    if (lane == 0) unsafeAtomicAdd(&cnts[b], 1.0f);
  }
}

// ---------------- conv (fallback, R4-proven): LDS weights + readlane ----------------
__global__ __launch_bounds__(256) void conv_csr_k(
    const int* __restrict__ rowptr, const int* __restrict__ srcs, const int* __restrict__ eids,
    const float* __restrict__ ea, const float* __restrict__ Wf, const float* __restrict__ Ws,
    const float* __restrict__ Af, const float* __restrict__ Bf,
    const float* __restrict__ As, const float* __restrict__ Bs,
    const float* __restrict__ hprev, float* __restrict__ out,
    const int* __restrict__ batch, float* __restrict__ sums, float* __restrict__ cnts, int do_pool)
{
  __shared__ float wfe[32*128];
  __shared__ float wse[32*128];
  int tid = threadIdx.x;
  #pragma unroll
  for (int q=0;q<4;++q){
    reinterpret_cast<float4*>(wfe)[tid + q*256] = reinterpret_cast<const float4*>(Wf + 256*128)[tid + q*256];
    reinterpret_cast<float4*>(wse)[tid + q*256] = reinterpret_cast<const float4*>(Ws + 256*128)[tid + q*256];
  }
  __syncthreads();
  int d = blockIdx.x*4 + (tid>>6);
  int lane = tid & 63;
  int c2 = lane*2;
  int beg = rowptr[d], end = rowptr[d+1];
  float2 afv = *reinterpret_cast<const float2*>(&Af[(size_t)d*128 + c2]);
  float2 asv = *reinterpret_cast<const float2*>(&As[(size_t)d*128 + c2]);
  float2 acc = make_float2(0.f, 0.f);
  int j16 = lane >> 4;
  int p   = lane & 15;
  for (int e0 = beg; e0 < end; e0 += 4){
    int nb = end - e0; nb = nb < 4 ? nb : 4;
    int em = 0, sm = 0;
    if (lane < nb){ em = eids[e0+lane]; sm = srcs[e0+lane]; }
    int erow = __shfl(em, j16);
    float2 ev = make_float2(0.f, 0.f);
    if (j16 < nb) ev = *reinterpret_cast<const float2*>(&ea[(size_t)erow*32 + p*2]);
    float2 Fj[4], Sj[4];
    #pragma unroll
    for (int jj=0;jj<4;++jj){
      int sj = __shfl(sm, jj);
      float2 bfv = make_float2(0.f,0.f), bsv = make_float2(0.f,0.f);
      if (jj < nb){
        bfv = *reinterpret_cast<const float2*>(&Bf[(size_t)sj*128 + c2]);
        bsv = *reinterpret_cast<const float2*>(&Bs[(size_t)sj*128 + c2]);
      }
      Fj[jj] = make_float2(afv.x+bfv.x, afv.y+bfv.y);
      Sj[jj] = make_float2(asv.x+bsv.x, asv.y+bsv.y);
    }
    #pragma unroll
    for (int k=0;k<32;++k){
      float2 wf2 = *reinterpret_cast<const float2*>(&wfe[k*128 + c2]);
      float2 ws2 = *reinterpret_cast<const float2*>(&wse[k*128 + c2]);
      #pragma unroll
      for (int jj=0;jj<4;++jj){
        int evi = __builtin_amdgcn_readlane(__float_as_int((k & 1) ? ev.y : ev.x), jj*16 + (k>>1));
        float evk = __int_as_float(evi);
        Fj[jj].x = fmaf(evk, wf2.x, Fj[jj].x);
        Fj[jj].y = fmaf(evk, wf2.y, Fj[jj].y);
        Sj[jj].x = fmaf(evk, ws2.x, Sj[jj].x);
        Sj[jj].y = fmaf(evk, ws2.y, Sj[jj].y);
      }
    }
    #pragma unroll
    for (int jj=0;jj<4;++jj){
      if (jj < nb){
        acc.x += sigmoidf_(Fj[jj].x)*softplusf_(Sj[jj].x);
        acc.y += sigmoidf_(Fj[jj].y)*softplusf_(Sj[jj].y);
      }
    }
  }
  float2 hv = *reinterpret_cast<const float2*>(&hprev[(size_t)d*128 + c2]);
  float ox = fmaxf(hv.x + acc.x, 0.f);
  float oy = fmaxf(hv.y + acc.y, 0.f);
  if (!do_pool){
    *reinterpret_cast<float2*>(&out[(size_t)d*128 + c2]) = make_float2(ox, oy);
  } else {
    int b = batch[d];
    unsafeAtomicAdd(&sums[(size_t)b*128 + c2 + 0], ox);
    unsafeAtomicAdd(&sums[(size_t)b*128 + c2 + 1], oy);
    if (lane == 0) unsafeAtomicAdd(&cnts[b], 1.0f);
  }
}

// ---------------- final: mean -> fc1(relu) -> 5 heads ----------------
__global__ __launch_bounds__(128) void final_k(const float* __restrict__ sums, const float* __restrict__ counts,
    const float* __restrict__ Wfc, const float* __restrict__ bfc,
    const float* __restrict__ Wh, const float* __restrict__ bh, float* __restrict__ outp)
{
  __shared__ float mean[128];
  __shared__ float gv[128];
  int g = blockIdx.x, t = threadIdx.x;
  float cnt = fmaxf(counts[g], 1.0f);
  mean[t] = sums[(size_t)g*128+t] / cnt;
  __syncthreads();
  float acc = bfc[t];
  #pragma unroll 8
  for (int k=0;k<128;++k) acc = fmaf(mean[k], Wfc[k*128+t], acc);
  gv[t] = fmaxf(acc, 0.0f);
  __syncthreads();
  if (t < 5){
    float o = bh[t];
    for (int k=0;k<128;++k) o = fmaf(gv[k], Wh[k*5+t], o);
    outp[g*5+t] = o;
  }
}

extern "C" void kernel_launch(void* const* d_in, const int* in_sizes, int n_in,
                              void* d_out, int out_size, void* d_ws, size_t ws_size,
                              hipStream_t stream) {
  const float* x    = (const float*)d_in[0];
  const float* ea   = (const float*)d_in[1];
  const int*   eidx = (const int*)  d_in[2];
  const int*   batch= (const int*)  d_in[3];
  const float* W1f  = (const float*)d_in[4];
  const float* b1f  = (const float*)d_in[5];
  const float* W1s  = (const float*)d_in[6];
  const float* b1s  = (const float*)d_in[7];
  const float* Wp   = (const float*)d_in[8];
  const float* bp   = (const float*)d_in[9];
  const float* W2f  = (const float*)d_in[10];
  const float* b2f  = (const float*)d_in[11];
  const float* W2s  = (const float*)d_in[12];
  const float* b2s  = (const float*)d_in[13];
  const float* W3f  = (const float*)d_in[14];
  const float* b3f  = (const float*)d_in[15];
  const float* W3s  = (const float*)d_in[16];
  const float* b3s  = (const float*)d_in[17];
  const float* Wfc  = (const float*)d_in[18];
  const float* bfc  = (const float*)d_in[19];
  const float* Wh   = (const float*)d_in[20];
  const float* bh   = (const float*)d_in[21];

  int E = in_sizes[2]/2;
  const int* srcp = eidx;
  const int* dstp = eidx + E;

  float* ws = (float*)d_ws;
  size_t o = 0;
  float* h1   = ws + o; o += 150016;
  float* h    = ws + o; o += (size_t)NN*128;
  float* h2   = ws + o; o += (size_t)NN*128;
  float* Af   = ws + o; o += (size_t)NN*128;
  float* Bf   = ws + o; o += (size_t)NN*128;
  float* As   = ws + o; o += (size_t)NN*128;
  float* Bs   = ws + o; o += (size_t)NN*128;
  float* sums = ws + o; o += (size_t)NG*128;
  float* cnts = ws + o; o += 512;
  int* iws    = (int*)(ws + o);
  size_t io = 0;
  int* deg    = iws + io; io += NN;
  int* rowptr = iws + io; io += NN + 64;
  int* cursor = iws + io; io += NN;
  int* srcs   = iws + io; io += (size_t)NE;
  int* eids   = iws + io; io += (size_t)NE;
  // T (bf16, [E][256]) after the int region, 256B-aligned
  size_t t_off_bytes = (o*4 + io*4 + 255) & ~(size_t)255;
  unsigned short* Tb = (unsigned short*)((char*)d_ws + t_off_bytes);
  size_t need = t_off_bytes + (size_t)E*256*2;
  int use_T = (ws_size >= need) ? 1 : 0;

  int ngAB   = (NN + 31)/32;
  int ngNode = (NN*128)/256;
  int ngE    = (E + 255)/256;
  int ngCsr  = NN/4;

  init_k<<<(NN*3 + 255)/256, 256, 0, stream>>>(x, h1, sums, cnts, deg);
  hist_k<<<ngE, 256, 0, stream>>>(dstp, deg, E);
  scan_k<<<1, 1024, 0, stream>>>(deg, rowptr, cursor);
  perm_k<<<ngE, 256, 0, stream>>>(srcp, dstp, cursor, srcs, eids, E);
  conv1_k<<<ngE, 256, 0, stream>>>(srcp, dstp, x, ea, W1f, b1f, W1s, b1s, h1, E);
  proj_k<<<ngNode, 256, 0, stream>>>(h1, Wp, bp, h);

  if (use_T){
    // conv2
    gemm_ab_k<<<ngAB, 256, 0, stream>>>(h, W2f, b2f, W2s, b2s, Af, Bf, As, Bs, NN);
    tgemm_k<<<1024, 256, 0, stream>>>(eids, ea, W2f, W2s, Tb, E);
    conv_t_k<<<ngCsr, 256, 0, stream>>>(rowptr, srcs, Tb, Af, Bf, As, Bs,
                                        h, h2, batch, sums, cnts, 0);
    // conv3
    gemm_ab_k<<<ngAB, 256, 0, stream>>>(h2, W3f, b3f, W3s, b3s, Af, Bf, As, Bs, NN);
    tgemm_k<<<1024, 256, 0, stream>>>(eids, ea, W3f, W3s, Tb, E);
    conv_t_k<<<ngCsr, 256, 0, stream>>>(rowptr, srcs, Tb, Af, Bf, As, Bs,
                                        h2, h, batch, sums, cnts, 1);
  } else {
    gemm_ab_k<<<ngAB, 256, 0, stream>>>(h, W2f, b2f, W2s, b2s, Af, Bf, As, Bs, NN);
    conv_csr_k<<<ngCsr, 256, 0, stream>>>(rowptr, srcs, eids, ea, W2f, W2s, Af, Bf, As, Bs,
                                          h, h2, batch, sums, cnts, 0);
    gemm_ab_k<<<ngAB, 256, 0, stream>>>(h2, W3f, b3f, W3s, b3s, Af, Bf, As, Bs, NN);
    conv_csr_k<<<ngCsr, 256, 0, stream>>>(rowptr, srcs, eids, ea, W3f, W3s, Af, Bf, As, Bs,
                                          h2, h, batch, sums, cnts, 1);
  }
  final_k<<<NG, 128, 0, stream>>>(sums, cnts, Wfc, bfc, Wh, bh, (float*)d_out);
}